// Round 17
// baseline (85.763 us; speedup 1.0000x reference)
//
#include <hip/hip_runtime.h>
#include <hip/hip_bf16.h>

#define BB   16
#define EMB  768
#define CIN  64
#define COUT 64
#define HH   112
#define WW   112
#define HID  192
#define TOTAL 36864                 // COUT*CIN*9
#define KSZ  576                    // CIN*9
#define SCOLS 114                   // padded cols (-1..112)
#define CSTR  80                    // LDS cell stride: 64 B data + 16 B pad (kills 128B-mult banking)
#define LROW  (SCOLS * CSTR)        // 9120 B per staged row

typedef short bf16x8 __attribute__((ext_vector_type(8)));
typedef float f32x4  __attribute__((ext_vector_type(4)));
typedef int   i32x4  __attribute__((ext_vector_type(4)));
typedef int   i32x2  __attribute__((ext_vector_type(2)));

static __device__ __forceinline__ unsigned short f2bf(float f) {
    unsigned u = __float_as_uint(f);
    u += 0x7FFF + ((u >> 16) & 1);          // RNE
    return (unsigned short)(u >> 16);
}

static __device__ __forceinline__ bf16x8 pack8(const float* v) {
    bf16x8 r;
    #pragma unroll
    for (int j = 0; j < 8; ++j) r[j] = (short)f2bf(v[j]);
    return r;
}

// ---- K1: mlp1  h = relu(cls @ W1 + b1).  192 blocks = 16b x 12jg ----
__global__ __launch_bounds__(256) void mlp1_kernel(const float* __restrict__ cls,
                                                   const float* __restrict__ W1,
                                                   const float* __restrict__ b1,
                                                   float* __restrict__ h) {
    __shared__ float xs[EMB];
    __shared__ float red[16][17];
    const int b   = blockIdx.x / 12;
    const int jg  = blockIdx.x - 12 * b;
    const int tid = threadIdx.x;
    for (int i = tid; i < EMB; i += 256) xs[i] = cls[b * EMB + i];
    __syncthreads();
    const int j16 = tid & 15;
    const int kq  = tid >> 4;
    const int j   = jg * 16 + j16;
    float acc = 0.f;
    #pragma unroll
    for (int k = kq * 48; k < kq * 48 + 48; ++k) acc += xs[k] * W1[k * HID + j];
    red[j16][kq] = acc;
    __syncthreads();
    if (tid < 16) {
        float s = b1[jg * 16 + tid];
        #pragma unroll
        for (int q = 0; q < 16; ++q) s += red[tid][q];
        h[b * HID + jg * 16 + tid] = fmaxf(s, 0.f);
    }
}

// ---- K2: MFMA GEMM  params = tanh(h @ W2 + b2) (+ identity at center tap) ----
__global__ __launch_bounds__(256) void mlp2_kernel(const float* __restrict__ h,
                                                   const float* __restrict__ W2,
                                                   const float* __restrict__ b2,
                                                   unsigned short* __restrict__ Ag) {
    __shared__ float hs[16 * 193];
    const int tid = threadIdx.x;
    for (int i = tid; i < BB * HID; i += 256) {
        const int bb = i / HID;
        hs[bb * 193 + (i - bb * HID)] = h[i];
    }
    __syncthreads();
    const int wave = tid >> 6;
    const int lane = tid & 63;
    const int lg   = lane >> 4;
    const int ln   = lane & 15;
    const int t0   = (blockIdx.x * 4 + wave) * 16;

    bf16x8 a6[6];
    #pragma unroll
    for (int kk = 0; kk < 6; ++kk) {
        float v[8];
        #pragma unroll
        for (int j = 0; j < 8; ++j) v[j] = hs[ln * 193 + kk * 32 + lg * 8 + j];
        a6[kk] = pack8(v);
    }

    f32x4 acc = (f32x4){0.f, 0.f, 0.f, 0.f};
    #pragma unroll
    for (int kk = 0; kk < 6; ++kk) {
        float w[8];
        #pragma unroll
        for (int j = 0; j < 8; ++j)
            w[j] = W2[(size_t)(kk * 32 + lg * 8 + j) * TOTAL + t0 + ln];
        acc = __builtin_amdgcn_mfma_f32_16x16x32_bf16(a6[kk], pack8(w), acc, 0, 0, 0);
    }

    const int t    = t0 + ln;
    const float bias = b2[t];
    const int co  = t / KSZ;
    const int rem = t - co * KSZ;
    const int ci  = rem / 9;
    const int p9  = rem - ci * 9;
    const float idv = (p9 == 4 && co == ci) ? 1.f : 0.f;
    unsigned short* pA = Ag + (size_t)(p9 * 64 + co) * 64 + ci;
    #pragma unroll
    for (int rg = 0; rg < 4; ++rg) {
        const int bi = lg * 4 + rg;
        pA[(size_t)bi * TOTAL] = f2bf(tanhf(acc[rg] + bias) + idv);
    }
}

// -------- K3: conv MFMA implicit GEMM (r9 structure, 80-B cell stride) --------
// Block: 256 thr / 4 waves; wave = (co-half cog, out-row r). 64 co x 2 rows x 112 px.
// LDS per half: 4 rows x 114 cells x 80 B (64 B data + 16 B pad) = 36480 B.
// Slice swizzle sl = (octet ^ (cell&3) ^ row)&3, identical formula on write/read;
// cell*80 decorrelates banks (cell*20 mod 32) -> staged writes ~conflict-free,
// reads exactly at the 8-requests/bank data-rate floor.
// Schedule: stage(h0) | bar | compute(h0) | bar | stage(h1) | bar | compute(h1).
__global__ __launch_bounds__(256, 4) void conv_kernel(const float* __restrict__ feat,
                                                      const unsigned short* __restrict__ Ag,
                                                      float* __restrict__ out) {
    __shared__ __align__(16) char lds[4 * LROW];    // 36480 B
    const int tid = threadIdx.x;
    // XCD-chunked swizzle: each XCD owns 112 consecutive logical blocks (= 2 batches)
    const int bid  = (blockIdx.x & 7) * 112 + (blockIdx.x >> 3);
    const int b    = bid / 56;
    const int tile = bid - b * 56;
    const int y0   = tile * 2;

    const int wave = tid >> 6;
    const int lane = tid & 63;
    const int cog  = wave & 1;
    const int r    = wave >> 1;
    const int lg   = lane >> 4;
    const int ln   = lane & 15;

    // staging thread mapping
    const int so = tid >> 6;                        // ci octet within half 0..3
    const int sr = (tid >> 4) & 3;                  // staged row 0..3
    const int sx = tid & 15;                        // 8-px chunk, active < 14
    const int sy = y0 - 1 + sr;
    const bool sact = (sx < 14);
    const bool syv  = sact && ((unsigned)sy < HH);
    char* ldsr = lds + sr * LROW;
    const f32x4 z4 = {0.f, 0.f, 0.f, 0.f};

    f32x4 acc[2][7];
    #pragma unroll
    for (int ct = 0; ct < 2; ++ct)
        #pragma unroll
        for (int t = 0; t < 7; ++t) acc[ct][t] = (f32x4){0.f, 0.f, 0.f, 0.f};

    const unsigned short* Ab = Ag + (size_t)b * 9 * 4096;

    // zero x-halo cells (0, 113) for all 4 rows (persist across both halves)
    if (tid < 32) {
        const int zr = tid >> 3, zc = ((tid >> 2) & 1) ? (SCOLS - 1) : 0, zs = tid & 3;
        *(i32x4*)(lds + zr * LROW + zc * CSTR + zs * 16) = (i32x4){0, 0, 0, 0};
    }

    #pragma unroll
    for (int h = 0; h < 2; ++h) {
        // ---- stage half h ----
        if (h) __syncthreads();                      // compute(h-1) done before overwrite
        if (sact) {
            const float* fp = feat + (((size_t)b * CIN + h * 32 + so * 8) * HH + sy) * WW + 8 * sx;
            #pragma unroll
            for (int jb = 0; jb < 2; ++jb) {
                f32x4 v[4][2];
                #pragma unroll
                for (int j = 0; j < 4; ++j)
                    #pragma unroll
                    for (int c = 0; c < 2; ++c)
                        v[j][c] = syv ? *(const f32x4*)(fp + (size_t)(jb * 4 + j) * (HH * WW) + 4 * c)
                                      : z4;
                #pragma unroll
                for (int i = 0; i < 8; ++i) {
                    const int i2   = (i + sx) & 7;   // px rotation: cell&3 varies per lane
                    const int cell = 8 * sx + i2 + 1;
                    const int sl   = (so ^ (cell & 3) ^ sr) & 3;
                    const int c = i2 >> 2, e = i2 & 3;
                    const unsigned d0 = (unsigned)f2bf(v[0][c][e]) | ((unsigned)f2bf(v[1][c][e]) << 16);
                    const unsigned d1 = (unsigned)f2bf(v[2][c][e]) | ((unsigned)f2bf(v[3][c][e]) << 16);
                    *(i32x2*)(ldsr + cell * CSTR + sl * 16 + jb * 8) = (i32x2){(int)d0, (int)d1};
                }
            }
        }
        __syncthreads();

        // ---- compute half h ----
        #pragma unroll
        for (int p9 = 0; p9 < 9; ++p9) {
            const int kh = p9 / 3, kw = p9 - 3 * kh;
            const int rs = r + kh;
            const bf16x8 a0 = *(const bf16x8*)(Ab + (size_t)(p9 * 64 + cog * 32 + ln) * 64
                                               + h * 32 + lg * 8);
            const bf16x8 a1 = *(const bf16x8*)(Ab + (size_t)(p9 * 64 + cog * 32 + 16 + ln) * 64
                                               + h * 32 + lg * 8);
            const char* lbase = lds + rs * LROW;
            #pragma unroll
            for (int t = 0; t < 7; ++t) {
                const int cell = ln + kw + 16 * t;
                const int sl   = (lg ^ (cell & 3) ^ rs) & 3;
                const bf16x8 bf = *(const bf16x8*)(lbase + cell * CSTR + sl * 16);
                acc[0][t] = __builtin_amdgcn_mfma_f32_16x16x32_bf16(a0, bf, acc[0][t], 0, 0, 0);
                acc[1][t] = __builtin_amdgcn_mfma_f32_16x16x32_bf16(a1, bf, acc[1][t], 0, 0, 0);
            }
        }
    }

    // ---- epilogue: nontemporal stores (residual folded into A) ----
    const int y = y0 + r;
    float* ob = out + (((size_t)b * COUT + cog * 32 + lg * 4) * HH + y) * WW + ln;
    #pragma unroll
    for (int ct = 0; ct < 2; ++ct)
        #pragma unroll
        for (int t = 0; t < 7; ++t)
            #pragma unroll
            for (int rg = 0; rg < 4; ++rg)
                __builtin_nontemporal_store(acc[ct][t][rg],
                    ob + ((size_t)(ct * 16 + rg)) * HH * WW + t * 16);
}

extern "C" void kernel_launch(void* const* d_in, const int* in_sizes, int n_in,
                              void* d_out, int out_size, void* d_ws, size_t ws_size,
                              hipStream_t stream) {
    const float* cls      = (const float*)d_in[0];
    const float* features = (const float*)d_in[1];
    const float* W1       = (const float*)d_in[2];
    const float* b1       = (const float*)d_in[3];
    const float* W2       = (const float*)d_in[4];
    const float* b2       = (const float*)d_in[5];
    float* out = (float*)d_out;

    float*          h  = (float*)d_ws;                       // 12 KB
    unsigned short* Ag = (unsigned short*)(h + BB * HID);    // 1.18 MB bf16 A[b][p9][co][ci]

    mlp1_kernel<<<192, 256, 0, stream>>>(cls, W1, b1, h);
    mlp2_kernel<<<TOTAL / 64, 256, 0, stream>>>(h, W2, b2, Ag);
    conv_kernel<<<56 * BB, 256, 0, stream>>>(features, Ag, out);
}